// Round 4
// baseline (85.738 us; speedup 1.0000x reference)
//
#include <hip/hip_runtime.h>
#include <hip/hip_bf16.h>

#define NN 8192
#define DD 64
#define SPLIT 4   // j-range splits per 16-row group

typedef __attribute__((ext_vector_type(8))) short short8;
typedef __attribute__((ext_vector_type(4))) float f32x4;

// exact-value helper (probe constants only; hot loop uses native __bf16 cast)
__device__ inline ushort f2bf(float f) {
    union { float f; unsigned u; } v; v.f = f;
    unsigned u = v.u;
    unsigned r = (u + 0x7FFFu + ((u >> 16) & 1u)) >> 16;
    return (ushort)r;
}

__device__ inline short f2bf_hw(float f) {
    __bf16 b = (__bf16)f;                       // compiler emits v_cvt_pk_bf16_f32 pairs
    return (short)__builtin_bit_cast(unsigned short, b);
}

// Kernel 1: src[i] = h[i,:]·a1 , dst[i] = h[i,:]·a2   (wave per row)
__global__ __launch_bounds__(256) void srcdst_kernel(
    const float* __restrict__ h, const float* __restrict__ a,
    float* __restrict__ src, float* __restrict__ dst)
{
    int row  = blockIdx.x * 4 + (threadIdx.x >> 6);
    int lane = threadIdx.x & 63;
    float v = h[(size_t)row * DD + lane];
    float s = v * a[lane];
    float t = v * a[DD + lane];
    #pragma unroll
    for (int m = 32; m; m >>= 1) {
        s += __shfl_xor(s, m);
        t += __shfl_xor(t, m);
    }
    if (lane == 0) { src[row] = s; dst[row] = t; }
}

// Kernel 2: pack h into bf16 MFMA-B-fragment order, 5 tiles per 32-chunk:
// t=0..3: HB[c][t][l][e] = bf16( h[ c*32 + (l>>4)*8 + e ][ t*16 + (l&15) ] )
// t=4   : ones-column tile (col 0 = 1.0, cols 1..15 = 0) -> row-sum via MFMA
__global__ __launch_bounds__(256) void pack_kernel(
    const float* __restrict__ h, ushort* __restrict__ HB)
{
    int tid = blockIdx.x * 256 + threadIdx.x;   // 0 .. 256*2560-1
    int c   = tid / 2560;
    int rem = tid - c * 2560;
    int t   = rem >> 9;
    int l   = (rem >> 3) & 63;
    int e   = rem & 7;
    ushort v;
    if (t < 4) {
        int row = c * 32 + ((l >> 4) << 3) + e;
        int col = t * 16 + (l & 15);
        v = f2bf(h[(size_t)row * DD + col]);
    } else {
        v = ((l & 15) == 0) ? (ushort)0x3F80 : (ushort)0;  // bf16 1.0 / 0.0
    }
    HB[tid] = v;
}

// Kernel 3: flash-style masked softmax + PV via bf16 MFMA.
__global__ __launch_bounds__(256, 8) void gat_main(
    const int*   __restrict__ adj,
    const float* __restrict__ src,
    const float* __restrict__ dst,
    const ushort* __restrict__ HB,
    float* __restrict__ po,   // [grid][16][64]
    float* __restrict__ pl)   // [grid][16]
{
    int tid  = threadIdx.x;
    int w    = tid >> 6;
    int lane = tid & 63;
    int r    = lane & 15;   // row label (P-row / src / adj row)
    int g    = lane >> 4;
    int ig   = blockIdx.x / SPLIT;
    int sp   = blockIdx.x % SPLIT;
    int i0   = ig * 16;

    // ---- MFMA layout self-probe (exact; C-write is mapping-agnostic) ----
    short8 lab, uni;
    {
        ushort lv = f2bf((float)r);
        ushort uv = f2bf(1.0f / 32.0f);
        #pragma unroll
        for (int e = 0; e < 8; ++e) { lab[e] = (short)lv; uni[e] = (short)uv; }
    }
    f32x4 zf = {};
    f32x4 t_row = __builtin_amdgcn_mfma_f32_16x16x32_bf16(lab, uni, zf, 0, 0, 0);
    f32x4 t_col = __builtin_amdgcn_mfma_f32_16x16x32_bf16(uni, lab, zf, 0, 0, 0);
    int rcode = 0, ccode = 0;
    #pragma unroll
    for (int q = 0; q < 4; ++q) {
        rcode |= ((int)(t_row[q] + 0.5f)) << (8 * q);
        ccode |= ((int)(t_col[q] + 0.5f)) << (8 * q);
    }

    float srcv = src[i0 + r];
    f32x4 acc[5] = {};

    const int jbase = sp * (NN / SPLIT) + w * (NN / SPLIT / 4);
    const int*    ap = adj + (size_t)(i0 + r) * NN + jbase + g * 8;
    const float*  dp = dst + jbase + g * 8;
    const ushort* hp = HB + (size_t)(jbase >> 5) * 2560 + lane * 8;

    for (int c = 0; c < (NN / SPLIT / 4) / 32; ++c) {
        int4   a0 = *reinterpret_cast<const int4*>(ap);
        int4   a1 = *reinterpret_cast<const int4*>(ap + 4);
        float4 d0 = *reinterpret_cast<const float4*>(dp);
        float4 d1 = *reinterpret_cast<const float4*>(dp + 4);
        int   am[8] = {a0.x, a0.y, a0.z, a0.w, a1.x, a1.y, a1.z, a1.w};
        float dv[8] = {d0.x, d0.y, d0.z, d0.w, d1.x, d1.y, d1.z, d1.w};
        short8 af;
        #pragma unroll
        for (int e = 0; e < 8; ++e) {
            float ev = srcv + dv[e];
            ev = fmaxf(ev, 0.01f * ev);          // leaky relu (slope < 1)
            float pe = (am[e] > 0) ? __expf(ev) : 0.f;
            af[e] = f2bf_hw(pe);
        }
        #pragma unroll
        for (int t = 0; t < 5; ++t) {
            short8 bf = *reinterpret_cast<const short8*>(hp + t * 512);
            acc[t] = __builtin_amdgcn_mfma_f32_16x16x32_bf16(af, bf, acc[t], 0, 0, 0);
        }
        ap += 32; dp += 32; hp += 2560;
    }

    __shared__ float o_sh[4][16][64];
    __shared__ float l_sh[4][16];
    #pragma unroll
    for (int t = 0; t < 4; ++t)
        #pragma unroll
        for (int q = 0; q < 4; ++q)
            o_sh[w][(rcode >> (8 * q)) & 15][t * 16 + ((ccode >> (8 * q)) & 15)] = acc[t][q];
    #pragma unroll
    for (int q = 0; q < 4; ++q)
        if (((ccode >> (8 * q)) & 15) == 0)
            l_sh[w][(rcode >> (8 * q)) & 15] = acc[4][q];
    __syncthreads();

    float* pob = po + ((size_t)blockIdx.x) * 16 * 64;
    for (int it = tid; it < 16 * 64; it += 256) {
        int row = it >> 6, d = it & 63;
        pob[it] = o_sh[0][row][d] + o_sh[1][row][d] + o_sh[2][row][d] + o_sh[3][row][d];
    }
    if (tid < 16)
        pl[(size_t)blockIdx.x * 16 + tid] =
            l_sh[0][tid] + l_sh[1][tid] + l_sh[2][tid] + l_sh[3][tid];
}

// Kernel 4: combine SPLIT partials, divide, write out.
__global__ __launch_bounds__(256) void reduce_kernel(
    const float* __restrict__ po, const float* __restrict__ pl,
    float* __restrict__ out)
{
    int idx = blockIdx.x * 256 + threadIdx.x;   // 0 .. NN*DD-1
    int row = idx >> 6;
    int d   = idx & 63;
    int ig  = row >> 4;
    int r   = row & 15;
    float o = 0.f, l = 0.f;
    #pragma unroll
    for (int sp = 0; sp < SPLIT; ++sp) {
        int b = ig * SPLIT + sp;
        o += po[((size_t)b * 16 + r) * 64 + d];
        l += pl[(size_t)b * 16 + r];
    }
    out[idx] = o / l;
}

extern "C" void kernel_launch(void* const* d_in, const int* in_sizes, int n_in,
                              void* d_out, int out_size, void* d_ws, size_t ws_size,
                              hipStream_t stream) {
    const float* h   = (const float*)d_in[0];
    const int*   adj = (const int*)d_in[1];
    const float* a   = (const float*)d_in[2];
    float* out = (float*)d_out;

    char* ws = (char*)d_ws;
    float*  src = (float*)ws;                       // 32 KB
    float*  dst = src + NN;                         // 32 KB
    ushort* HB  = (ushort*)(ws + (1u << 16));       // 1.31 MB (5 tiles/chunk)
    float*  po  = (float*)(ws + (2u << 20));        // 8 MB
    float*  pl  = (float*)(ws + (12u << 20));       // 128 KB

    srcdst_kernel<<<NN / 4, 256, 0, stream>>>(h, a, src, dst);
    pack_kernel<<<(NN / 32) * 2560 / 256, 256, 0, stream>>>(h, HB);
    gat_main<<<(NN / 16) * SPLIT, 256, 0, stream>>>(adj, src, dst, HB, po, pl);
    reduce_kernel<<<(NN * DD) / 256, 256, 0, stream>>>(po, pl, out);
}

// Round 5
// 82.986 us; speedup vs baseline: 1.0332x; 1.0332x over previous
//
#include <hip/hip_runtime.h>
#include <hip/hip_bf16.h>

#define NN 8192
#define DD 64
#define SPLIT 4   // j-range splits per 16-row group

typedef __attribute__((ext_vector_type(8))) short short8;
typedef __attribute__((ext_vector_type(4))) float f32x4;

// exact-value helper (probe/pack constants)
__device__ inline ushort f2bf(float f) {
    union { float f; unsigned u; } v; v.f = f;
    unsigned u = v.u;
    unsigned r = (u + 0x7FFFu + ((u >> 16) & 1u)) >> 16;
    return (ushort)r;
}

__device__ inline short f2bf_hw(float f) {
    __bf16 b = (__bf16)f;                       // compiler emits v_cvt_pk_bf16_f32 pairs
    return (short)__builtin_bit_cast(unsigned short, b);
}

// Kernel 1: src[i] = h[i,:]·a1 , dst[i] = h[i,:]·a2   (wave per row)
__global__ __launch_bounds__(256) void srcdst_kernel(
    const float* __restrict__ h, const float* __restrict__ a,
    float* __restrict__ src, float* __restrict__ dst)
{
    int row  = blockIdx.x * 4 + (threadIdx.x >> 6);
    int lane = threadIdx.x & 63;
    float v = h[(size_t)row * DD + lane];
    float s = v * a[lane];
    float t = v * a[DD + lane];
    #pragma unroll
    for (int m = 32; m; m >>= 1) {
        s += __shfl_xor(s, m);
        t += __shfl_xor(t, m);
    }
    if (lane == 0) { src[row] = s; dst[row] = t; }
}

// Kernel 2: pack h (fp32) into bf16 MFMA-B-fragment order (4 tiles/chunk).
// HB[c][t][l][e] = bf16( h[ c*32 + (l>>4)*8 + e ][ t*16 + (l&15) ] )
__global__ __launch_bounds__(256) void pack_kernel(
    const float* __restrict__ h, ushort* __restrict__ HB)
{
    int tid = blockIdx.x * 256 + threadIdx.x;   // 0 .. N*DD-1
    int e = tid & 7;
    int l = (tid >> 3) & 63;
    int t = (tid >> 9) & 3;
    int c = tid >> 11;
    int row = c * 32 + ((l >> 4) << 3) + e;
    int col = t * 16 + (l & 15);
    HB[tid] = f2bf(h[(size_t)row * DD + col]);
}

// Kernel 3: flash-style masked softmax + PV via bf16 MFMA.
// adj is staged global->LDS coalesced (16 lines/instr instead of 64),
// per-wave private double buffer, then gathered as A-fragments via ds_read_b128.
__global__ __launch_bounds__(256, 8) void gat_main(
    const int*   __restrict__ adj,
    const float* __restrict__ src,
    const float* __restrict__ dst,
    const ushort* __restrict__ HB,
    float* __restrict__ po,   // [grid][16][64]
    float* __restrict__ pl)   // [grid][16]
{
    int tid  = threadIdx.x;
    int w    = tid >> 6;
    int lane = tid & 63;
    int r    = lane & 15;   // row label (P-row / src / adj row)
    int g    = lane >> 4;
    int ig   = blockIdx.x / SPLIT;
    int sp   = blockIdx.x % SPLIT;
    int i0   = ig * 16;

    // stage: per wave, 2 buffers of 16 rows x 36 ints (pad->16B-aligned rows).
    // 4*2*16*36*4 = 18432 B. o_sh (16384 B) overlays it after the loop.
    __shared__ char smem[18432];
    __shared__ float l_sh[4][16];
    int* stw = (int*)smem + w * 1152;           // this wave's two buffers

    // ---- MFMA layout self-probe (exact; C-write is mapping-agnostic) ----
    short8 lab, uni;
    {
        ushort lv = f2bf((float)r);
        ushort uv = f2bf(1.0f / 32.0f);
        #pragma unroll
        for (int e = 0; e < 8; ++e) { lab[e] = (short)lv; uni[e] = (short)uv; }
    }
    f32x4 zf = {};
    f32x4 t_row = __builtin_amdgcn_mfma_f32_16x16x32_bf16(lab, uni, zf, 0, 0, 0);
    f32x4 t_col = __builtin_amdgcn_mfma_f32_16x16x32_bf16(uni, lab, zf, 0, 0, 0);
    int rcode = 0, ccode = 0;
    #pragma unroll
    for (int q = 0; q < 4; ++q) {
        rcode |= ((int)(t_row[q] + 0.5f)) << (8 * q);
        ccode |= ((int)(t_col[q] + 0.5f)) << (8 * q);
    }

    float srcv = src[i0 + r];
    f32x4 acc[4] = {};
    float lsum = 0.f;

    const int jbase = sp * (NN / SPLIT) + w * (NN / SPLIT / 4);
    int srow = lane >> 2;                       // staging: 4 lanes per row
    int sg   = lane & 3;
    const int*    gsrc = adj + (size_t)(i0 + srow) * NN + jbase + sg * 4;
    const float*  dp   = dst + jbase + g * 8;
    const ushort* hp   = HB + (size_t)(jbase >> 5) * 2048 + lane * 8;

    // prologue: stage iter 0 into buffer 0
    {
        int4 A0 = *reinterpret_cast<const int4*>(gsrc);
        int4 A1 = *reinterpret_cast<const int4*>(gsrc + 16);
        gsrc += 32;
        *reinterpret_cast<int4*>(stw + srow * 36 + sg * 4)      = A0;
        *reinterpret_cast<int4*>(stw + srow * 36 + sg * 4 + 16) = A1;
    }

    #pragma unroll
    for (int c = 0; c < 16; ++c) {
        int4 nA0, nA1;
        if (c < 15) {                            // issue next-iter global loads early
            nA0 = *reinterpret_cast<const int4*>(gsrc);
            nA1 = *reinterpret_cast<const int4*>(gsrc + 16);
            gsrc += 32;
        }
        const int* mb = stw + (c & 1) * 576 + r * 36 + g * 8;
        int4 m0 = *reinterpret_cast<const int4*>(mb);
        int4 m1 = *reinterpret_cast<const int4*>(mb + 4);
        float4 d0 = *reinterpret_cast<const float4*>(dp);
        float4 d1 = *reinterpret_cast<const float4*>(dp + 4);
        dp += 32;
        int   am[8] = {m0.x, m0.y, m0.z, m0.w, m1.x, m1.y, m1.z, m1.w};
        float dv[8] = {d0.x, d0.y, d0.z, d0.w, d1.x, d1.y, d1.z, d1.w};
        short8 af;
        #pragma unroll
        for (int e = 0; e < 8; ++e) {
            float ev = srcv + dv[e];
            ev = fmaxf(ev, 0.01f * ev);          // leaky relu (slope < 1)
            float pe = (am[e] > 0) ? __expf(ev) : 0.f;
            lsum += pe;
            af[e] = f2bf_hw(pe);
        }
        #pragma unroll
        for (int t = 0; t < 4; ++t) {
            short8 bf = *reinterpret_cast<const short8*>(hp + t * 512);
            acc[t] = __builtin_amdgcn_mfma_f32_16x16x32_bf16(af, bf, acc[t], 0, 0, 0);
        }
        hp += 2048;
        if (c < 15) {                            // write-late into the other buffer
            int* wb = stw + ((c + 1) & 1) * 576 + srow * 36 + sg * 4;
            *reinterpret_cast<int4*>(wb)      = nA0;
            *reinterpret_cast<int4*>(wb + 16) = nA1;
        }
    }

    // denominator: sum across the 4 k-groups (lanes r, r+16, r+32, r+48)
    lsum += __shfl_xor(lsum, 16);
    lsum += __shfl_xor(lsum, 32);

    __syncthreads();                             // all staging reads done before o_sh overlay
    float (*o_sh)[16][64] = reinterpret_cast<float (*)[16][64]>(smem);
    #pragma unroll
    for (int t = 0; t < 4; ++t)
        #pragma unroll
        for (int q = 0; q < 4; ++q)
            o_sh[w][(rcode >> (8 * q)) & 15][t * 16 + ((ccode >> (8 * q)) & 15)] = acc[t][q];
    if (g == 0) l_sh[w][r] = lsum;
    __syncthreads();

    float* pob = po + ((size_t)blockIdx.x) * 16 * 64;
    for (int it = tid; it < 16 * 64; it += 256) {
        int row = it >> 6, d = it & 63;
        pob[it] = o_sh[0][row][d] + o_sh[1][row][d] + o_sh[2][row][d] + o_sh[3][row][d];
    }
    if (tid < 16)
        pl[(size_t)blockIdx.x * 16 + tid] =
            l_sh[0][tid] + l_sh[1][tid] + l_sh[2][tid] + l_sh[3][tid];
}

// Kernel 4: combine SPLIT partials, divide, write out.
__global__ __launch_bounds__(256) void reduce_kernel(
    const float* __restrict__ po, const float* __restrict__ pl,
    float* __restrict__ out)
{
    int idx = blockIdx.x * 256 + threadIdx.x;   // 0 .. NN*DD-1
    int row = idx >> 6;
    int d   = idx & 63;
    int ig  = row >> 4;
    int r   = row & 15;
    float o = 0.f, l = 0.f;
    #pragma unroll
    for (int sp = 0; sp < SPLIT; ++sp) {
        int b = ig * SPLIT + sp;
        o += po[((size_t)b * 16 + r) * 64 + d];
        l += pl[(size_t)b * 16 + r];
    }
    out[idx] = o / l;
}

extern "C" void kernel_launch(void* const* d_in, const int* in_sizes, int n_in,
                              void* d_out, int out_size, void* d_ws, size_t ws_size,
                              hipStream_t stream) {
    const float* h   = (const float*)d_in[0];
    const int*   adj = (const int*)d_in[1];
    const float* a   = (const float*)d_in[2];
    float* out = (float*)d_out;

    char* ws = (char*)d_ws;
    float*  src = (float*)ws;                       // 32 KB
    float*  dst = src + NN;                         // 32 KB
    ushort* HB  = (ushort*)(ws + (1u << 16));       // 1 MB (4 tiles/chunk)
    float*  po  = (float*)(ws + (2u << 20));        // 8 MB
    float*  pl  = (float*)(ws + (12u << 20));       // 128 KB

    srcdst_kernel<<<NN / 4, 256, 0, stream>>>(h, a, src, dst);
    pack_kernel<<<(NN * DD) / 256, 256, 0, stream>>>(h, HB);
    gat_main<<<(NN / 16) * SPLIT, 256, 0, stream>>>(adj, src, dst, HB, po, pl);
    reduce_kernel<<<(NN * DD) / 256, 256, 0, stream>>>(po, pl, out);
}